// Round 3
// baseline (536.766 us; speedup 1.0000x reference)
//
#include <hip/hip_runtime.h>
#include <stdint.h>
#include <string.h>
#include <math.h>

// ---------------------------------------------------------------------------
// FlashThermodynamicAttention — exact replication of the JAX reference.
// Bit-exact recipe (verified R0/R1, absmax = 0): partitionable threefry
// (counter (0, m), bits = y0 ^ y1), XLA:CPU Cephes expf (non-fused),
// betas via double-rounded log/exp (jit const-folding).
//
// R2: force minimal cipher codegen:
//   - rotations via __builtin_amdgcn_alignbit (1 instr) instead of shl/shr/or
//   - cipher specialized for c0 = 0: x0-init folded into round 1,
//     x1-init = one v_add of VGPR mbase with uniform (K1 + k)
//   - key-schedule constants precomputed as wave-uniform (SALU) values
// ---------------------------------------------------------------------------

struct FtaParams {
  uint32_t hk[32][2];   // threefry key for each of 16 steps x 2 half-sweeps
  uint32_t K9[2][9];    // (cutoff << 9): update to +1 iff bits < K9[beta][h+4]
};

// Host-side threefry-2x32 (key derivation only).
static inline void tf2x32_host(uint32_t k0, uint32_t k1, uint32_t c0, uint32_t c1,
                               uint32_t& o0, uint32_t& o1) {
  uint32_t ks2 = k0 ^ k1 ^ 0x1BD11BDAu;
  uint32_t x0 = c0 + k0, x1 = c1 + k1;
#define TFR(r) { x0 += x1; x1 = (x1 << (r)) | (x1 >> (32 - (r))); x1 ^= x0; }
  TFR(13) TFR(15) TFR(26) TFR(6)
  x0 += k1;  x1 += ks2 + 1u;
  TFR(17) TFR(29) TFR(16) TFR(24)
  x0 += ks2; x1 += k0 + 2u;
  TFR(13) TFR(15) TFR(26) TFR(6)
  x0 += k0;  x1 += k1 + 3u;
  TFR(17) TFR(29) TFR(16) TFR(24)
  x0 += k1;  x1 += ks2 + 4u;
  TFR(13) TFR(15) TFR(26) TFR(6)
  x0 += ks2; x1 += k0 + 5u;
#undef TFR
  o0 = x0; o1 = x1;
}

// Device threefry-2x32 specialized for counter (0, m); returns y0 ^ y1.
// Inputs: uniform key material; x1 = m + K1 (per-lane). All rotations are
// single v_alignbit_b32: rotl(x, r) == alignbit(x, x, 32 - r).
__device__ static inline uint32_t tf_bits(uint32_t K0, uint32_t K1, uint32_t ks2,
                                          uint32_t i1, uint32_t i2, uint32_t i3,
                                          uint32_t i4, uint32_t i5, uint32_t x1) {
#define ROTL(x, r) __builtin_amdgcn_alignbit((x), (x), 32u - (r))
  uint32_t x0 = K0 + x1;               // round 1 add (x0 init = 0 + K0 folded)
  x1 = ROTL(x1, 13) ^ x0;
  x0 += x1; x1 = ROTL(x1, 15) ^ x0;
  x0 += x1; x1 = ROTL(x1, 26) ^ x0;
  x0 += x1; x1 = ROTL(x1, 6)  ^ x0;
  x0 += K1; x1 += i1;                  // i1 = ks2 + 1
  x0 += x1; x1 = ROTL(x1, 17) ^ x0;
  x0 += x1; x1 = ROTL(x1, 29) ^ x0;
  x0 += x1; x1 = ROTL(x1, 16) ^ x0;
  x0 += x1; x1 = ROTL(x1, 24) ^ x0;
  x0 += ks2; x1 += i2;                 // i2 = K0 + 2
  x0 += x1; x1 = ROTL(x1, 13) ^ x0;
  x0 += x1; x1 = ROTL(x1, 15) ^ x0;
  x0 += x1; x1 = ROTL(x1, 26) ^ x0;
  x0 += x1; x1 = ROTL(x1, 6)  ^ x0;
  x0 += K0; x1 += i3;                  // i3 = K1 + 3
  x0 += x1; x1 = ROTL(x1, 17) ^ x0;
  x0 += x1; x1 = ROTL(x1, 29) ^ x0;
  x0 += x1; x1 = ROTL(x1, 16) ^ x0;
  x0 += x1; x1 = ROTL(x1, 24) ^ x0;
  x0 += K1; x1 += i4;                  // i4 = ks2 + 4
  x0 += x1; x1 = ROTL(x1, 13) ^ x0;
  x0 += x1; x1 = ROTL(x1, 15) ^ x0;
  x0 += x1; x1 = ROTL(x1, 26) ^ x0;
  x0 += x1; x1 = ROTL(x1, 6)  ^ x0;
  x0 += ks2; x1 += i5;                 // i5 = K0 + 5
  return x0 ^ x1;
#undef ROTL
}

// ---------------------------------------------------------------------------
// Device kernel: one thread per (b, h, n) 8x8 grid; spins as 64-bit bitboard.
// ---------------------------------------------------------------------------
__global__ __launch_bounds__(256) void fta_kernel(const float* __restrict__ v,
                                                  float* __restrict__ out,
                                                  FtaParams P) {
  uint32_t tid = blockIdx.x * 256u + threadIdx.x;   // tid = ((b*16+h)*4096+n)
  uint32_t b = tid >> 16;
  uint32_t h = (tid >> 12) & 15u;
  uint32_t n = tid & 4095u;

  // v / out layout: (B, N, D) with D = h*64 + (i*8+j); row is 64 contiguous floats.
  size_t voff = ((size_t)(b * 4096u + n)) * 1024u + (size_t)h * 64u;

  uint64_t bd = 0;  // bit k = i*8+j; 1 <-> spin +1
#pragma unroll
  for (int k = 0; k < 64; k += 4) {
    float4 a = *reinterpret_cast<const float4*>(v + voff + k);
    bd |= ((uint64_t)(a.x > 0.0f)) << (k + 0);
    bd |= ((uint64_t)(a.y > 0.0f)) << (k + 1);
    bd |= ((uint64_t)(a.z > 0.0f)) << (k + 2);
    bd |= ((uint64_t)(a.w > 0.0f)) << (k + 3);
  }

  uint32_t mbase = tid * 64u;  // flat index of site (b,h,n,0,0) in (B,H,N,8,8)

  // Threshold set for the current beta (switches at t == 8). Constant indices
  // only -> stays in registers.
  uint32_t K[9];
#pragma unroll
  for (int q = 0; q < 9; ++q) K[q] = P.K9[0][q];

  // Checkerboard masks: hf=0 updates (i+j) odd, hf=1 updates (i+j) even.
  const uint64_t PMASK[2] = { 0x55AA55AA55AA55AAull, 0xAA55AA55AA55AA55ull };

  for (int t = 0; t < 16; ++t) {
    if (t == 8) {
#pragma unroll
      for (int q = 0; q < 9; ++q) K[q] = P.K9[1][q];
    }
#pragma unroll
    for (int hf = 0; hf < 2; ++hf) {
      const uint32_t K0 = P.hk[2 * t + hf][0];
      const uint32_t K1 = P.hk[2 * t + hf][1];
      const uint32_t ks2 = K0 ^ K1 ^ 0x1BD11BDAu;
      const uint32_t i1 = ks2 + 1u, i2 = K0 + 2u, i3 = K1 + 3u,
                     i4 = ks2 + 4u, i5 = K0 + 5u;

      // ---- bit-sliced neighbor counts for all 64 sites ----
      uint64_t U = bd >> 8;                                   // s[i+1][j]
      uint64_t D = bd << 8;                                   // s[i-1][j]
      uint64_t L = (bd >> 1) & 0x7f7f7f7f7f7f7f7full;         // s[i][j+1]
      uint64_t R = (bd << 1) & 0xfefefefefefefefeull;         // s[i][j-1]
      uint64_t t0 = U ^ D, ca = U & D;
      uint64_t t1 = L ^ R, cb = L & R;
      uint64_t c0 = t0 ^ t1, cc = t0 & t1;
      uint64_t cx = ca ^ cb;
      uint64_t c1 = cx ^ cc;
      uint64_t c2 = (ca & cb) | (cc & cx);

      uint32_t accLo = 0u, accHi = 0u;
#pragma unroll
      for (int i = 0; i < 8; ++i) {
        const int j0 = (i + 1 + hf) & 1;
#pragma unroll
        for (int jj = 0; jj < 4; ++jj) {
          const int j = 2 * jj + j0;
          const int k = i * 8 + j;
          // counter m = mbase + k; x1 = m + K1 = mbase + (K1 + k) [uniform add]
          uint32_t bits = tf_bits(K0, K1, ks2, i1, i2, i3, i4, i5,
                                  mbase + (K1 + (uint32_t)k));

          uint32_t b0 = (uint32_t)(c0 >> k) & 1u;
          uint32_t b1 = (uint32_t)(c1 >> k) & 1u;
          // boundary class: e = #missing neighbors; idx = 2*cnt + e
          const int e = (int)(i == 0) + (int)(i == 7) + (int)(j == 0) + (int)(j == 7);
          uint32_t thr;
          if (e == 0) {            // interior: K[0,2,4,6,8] by cnt 0..4
            uint32_t b2 = (uint32_t)(c2 >> k) & 1u;
            uint32_t tA = b0 ? K[2] : K[0];
            uint32_t tB = b0 ? K[6] : K[4];
            uint32_t tC = b1 ? tB : tA;
            thr = b2 ? K[8] : tC;
          } else if (e == 1) {     // edge: K[1,3,5,7] by cnt 0..3
            uint32_t tA = b0 ? K[3] : K[1];
            uint32_t tB = b0 ? K[7] : K[5];
            thr = b1 ? tB : tA;
          } else {                 // corner: K[2,4,6] by cnt 0..2
            uint32_t tA = b0 ? K[4] : K[2];
            thr = b1 ? K[6] : tA;
          }

          uint32_t nb = (bits < thr) ? 1u : 0u;
          if (k < 32) accLo |= nb << k;
          else        accHi |= nb << (k - 32);
        }
      }
      uint64_t acc = ((uint64_t)accHi << 32) | (uint64_t)accLo;
      bd = (bd & ~PMASK[hf]) | acc;
    }
  }

#pragma unroll
  for (int k = 0; k < 64; k += 4) {
    float4 o;
    o.x = ((bd >> (k + 0)) & 1ull) ? 1.0f : -1.0f;
    o.y = ((bd >> (k + 1)) & 1ull) ? 1.0f : -1.0f;
    o.z = ((bd >> (k + 2)) & 1ull) ? 1.0f : -1.0f;
    o.w = ((bd >> (k + 3)) & 1ull) ? 1.0f : -1.0f;
    *reinterpret_cast<float4*>(out + voff + k) = o;
  }
}

// ---------------------------------------------------------------------------
// XLA:CPU vectorized expf (Cephes/Eigen pexp<float>), non-fused mul/add.
static float xla_expf(float xin) {
  const float exp_hi = 88.3762626647950f;
  const float exp_lo = -88.3762626647949f;
  const float LOG2EF = 1.44269504088896341f;
  const float C1 = 0.693359375f;
  const float C2 = -2.12194440e-4f;
  const float Pc0 = 1.9875691500E-4f;
  const float Pc1 = 1.3981999507E-3f;
  const float Pc2 = 8.3334519073E-3f;
  const float Pc3 = 4.1665795894E-2f;
  const float Pc4 = 1.6666665459E-1f;
  const float Pc5 = 5.0000001201E-1f;
#define MA(a, b, c) ((a) * (b) + (c))
  float x = xin;
  if (x > exp_hi) x = exp_hi;
  if (x < exp_lo) x = exp_lo;
  float fx = floorf(MA(x, LOG2EF, 0.5f));
  float tmp = C1 * fx;
  float z = C2 * fx;
  x = x - tmp;
  x = x - z;
  z = x * x;
  float y = MA(x, Pc0, Pc1);
  y = MA(y, x, Pc2);
  y = MA(y, x, Pc3);
  y = MA(y, x, Pc4);
  y = MA(y, x, Pc5);
  y = MA(y, z, x);
  y = y + 1.0f;
  int nn = (int)fx;
  uint32_t eb = (uint32_t)(nn + 127) << 23;
  float p2n;
  memcpy(&p2n, &eb, 4);
  float r = y * p2n;
  return r > xin ? r : xin;
#undef MA
}

extern "C" void kernel_launch(void* const* d_in, const int* in_sizes, int n_in,
                              void* d_out, int out_size, void* d_ws, size_t ws_size,
                              hipStream_t stream) {
  (void)in_sizes; (void)n_in; (void)d_ws; (void)ws_size; (void)out_size;
  const float* v = (const float*)d_in[2];  // inputs: q, k, v — only v used
  float* out = (float*)d_out;

  FtaParams P;

  // ---- key derivation (host, exact integer math) ----
  const uint32_t rk0 = 0u, rk1 = 1234u;  // jax.random.key(1234) -> (0, 1234)
  uint32_t kt[16][2];
  // partitionable fold-like split: child j = cipher(key, (0, j)) -> (y0, y1)
  for (uint32_t t = 0; t < 16; ++t) tf2x32_host(rk0, rk1, 0u, t, kt[t][0], kt[t][1]);
  for (int t = 0; t < 16; ++t) {
    uint32_t a0, a1, b0, b1;
    tf2x32_host(kt[t][0], kt[t][1], 0u, 0u, a0, a1);  // k0 (first half-sweep)
    tf2x32_host(kt[t][0], kt[t][1], 0u, 1u, b0, b1);  // k1 (second half-sweep)
    P.hk[2 * t + 0][0] = a0; P.hk[2 * t + 0][1] = a1;
    P.hk[2 * t + 1][0] = b0; P.hk[2 * t + 1][1] = b1;
  }

  // ---- betas: jit const-folding path (HloEvaluator -> double-rounded) ----
  float bet[2];
  bet[0] = (float)exp((double)(float)log((double)0.8f));
  bet[1] = (float)exp((double)(float)log((double)1.2f));

  // ---- sigmoid cutoffs: u < p  <=>  bits < (ceil(p * 2^23) << 9) ----
  for (int s = 0; s < 2; ++s) {
    float x2b = 2.0f * bet[s];
    for (int hh = -4; hh <= 4; ++hh) {
      float xh = x2b * (float)hh;       // fl(2*beta*h), as in JAX
      float e = xla_expf(-xh);          // exp(-x)
      float p = 1.0f / (1.0f + e);      // LogisticExpander form
      double pd = (double)p * 8388608.0;  // exact in double
      uint64_t kc = (uint64_t)ceil(pd);
      uint64_t k9 = kc << 9;
      P.K9[s][hh + 4] = (k9 > 0xFFFFFFFFull) ? 0xFFFFFFFFu : (uint32_t)k9;
    }
  }

  fta_kernel<<<dim3(1024), dim3(256), 0, stream>>>(v, out, P);
}